// Round 12
// baseline (548.200 us; speedup 1.0000x reference)
//
#include <hip/hip_runtime.h>
#include <hip/hip_bf16.h>

// BiDirectionalFusionModule on MI355X.
// R2: global_load_lds(16B) GEMM staging; coalesced weight preps.
// R5: MFMA attention (8 waves, wave-local softmax/LN, swizzled LDS, V via lds-DMA).
// R6: GEMM L2-locality (cib-outer/tap-inner, XCD chunk swizzle): FETCH 574->60MB.
// R7: Q-proj fused into attn_k; targeted border/tail zeroing.
// R9: 8-phase 256^2 GEMM (T3+T4+T5): 186us/conv, MfmaUtil 38% (measured best).
// R10: merged d2r/r2d tail; gemm256 resched regressed -> reverted.
// R11: measured-best recombination: 534.8us.
// R12: single isolated change: STG pair 3 moved phase3->phase2 (last-staged pair
//      gets >=2 phases of HBM-latency slack before the phase-0 counted wait).

typedef __bf16 bf16x8 __attribute__((ext_vector_type(8)));
typedef float f32x4 __attribute__((ext_vector_type(4)));

#define AS1 __attribute__((address_space(1)))
#define AS3 __attribute__((address_space(3)))
#define DEVI __device__ __forceinline__
#define BARRIER() do { asm volatile("" ::: "memory"); __builtin_amdgcn_s_barrier(); asm volatile("" ::: "memory"); } while (0)

DEVI float bf2f(unsigned short u){
  union { unsigned int i; float f; } v; v.i = ((unsigned int)u) << 16; return v.f;
}
DEVI unsigned short f2bf(float f){
  union { float f; unsigned int i; } v; v.f = f;
  unsigned int x = v.i;
  unsigned int r = (x + 0x7fffu + ((x >> 16) & 1u)) >> 16;
  return (unsigned short)r;
}

// ---------------------------------------------------------------- BN prep
__global__ void bnprep_k(const float* __restrict__ g1, const float* __restrict__ be1,
                         const float* __restrict__ m1, const float* __restrict__ v1,
                         const float* __restrict__ b1,
                         const float* __restrict__ gf, const float* __restrict__ bef,
                         const float* __restrict__ mf, const float* __restrict__ vf,
                         const float* __restrict__ bf,
                         float* __restrict__ sc1, float* __restrict__ sh1,
                         float* __restrict__ scf, float* __restrict__ shf)
{
  int c = threadIdx.x;
  float s = g1[c] * rsqrtf(v1[c] + 1e-5f);
  sc1[c] = s; sh1[c] = (b1[c] - m1[c]) * s + be1[c];
  s = gf[c] * rsqrtf(vf[c] + 1e-5f);
  scf[c] = s; shf[c] = (bf[c] - mf[c]) * s + bef[c];
}

// ---------------------------------------------------------------- targeted zeroing
__global__ __launch_bounds__(128)
void zero_border_k(unsigned short* __restrict__ buf, int px_el)
{
  int bi = blockIdx.x;
  int img = bi / 356, e = bi - img * 356;
  int y, x;
  if (e < 90){ y = 0; x = e; }
  else if (e < 180){ y = 89; x = e - 90; }
  else if (e < 268){ y = e - 180 + 1; x = 0; }
  else { y = e - 268 + 1; x = 89; }
  size_t pix = ((size_t)img * 90 + y) * 90 + x;
  int t = threadIdx.x;
  if (t < (px_el >> 3))
    *reinterpret_cast<uint4*>(buf + pix * px_el + t * 8) = uint4{0, 0, 0, 0};
}
__global__ __launch_bounds__(256)
void zero_fustail_k(unsigned short* __restrict__ FusPad)
{
  int idx = blockIdx.x * 256 + threadIdx.x;   // 61952*8
  int n = idx >> 3, ch = idx & 7;
  int b = n / 7744, s = n - b * 7744;
  int y = s / 88, x = s - y * 88;
  size_t pix = ((size_t)(b * 90 + y + 1)) * 90 + (x + 1);
  *reinterpret_cast<uint4*>(FusPad + pix * 576 + 512 + ch * 8) = uint4{0, 0, 0, 0};
}

// ------------------------------------------------- NCHW f32 -> padded NHWC bf16
__global__ __launch_bounds__(256)
void prep_xpad_k(const float* __restrict__ rgb, const float* __restrict__ dep,
                 unsigned short* __restrict__ Xpad)
{
  __shared__ unsigned short tile[64][65];
  int bi = blockIdx.x;
  int b = bi / 968;
  int rem = bi - b * 968;
  int cblk = rem / 121;
  int pblk = rem - cblk * 121;
  int t = threadIdx.x;
  int pl = t & 63;
  #pragma unroll
  for (int pass = 0; pass < 16; ++pass){
    int cl = pass * 4 + (t >> 6);
    int c = cblk * 64 + cl;
    const float* sp = (c < 256) ? (rgb + ((size_t)b * 256 + c) * 7744)
                                : (dep + ((size_t)b * 256 + (c - 256)) * 7744);
    tile[cl][pl] = f2bf(sp[pblk * 64 + pl]);
  }
  __syncthreads();
  int cl2 = t & 63;
  for (int pass = 0; pass < 16; ++pass){
    int pl2 = pass * 4 + (t >> 6);
    int pixg = pblk * 64 + pl2;
    int y = pixg / 88, x = pixg - y * 88;
    Xpad[(((size_t)b * 90 + y + 1) * 90 + (x + 1)) * 512 + cblk * 64 + cl2] = tile[cl2][pl2];
  }
}

// ---------------------------------------------------------------- weight reshuffles
__global__ __launch_bounds__(256)
void prep_w1t_k(const float* __restrict__ w, unsigned short* __restrict__ o)
{
  int co = blockIdx.x, t = threadIdx.x;
  const float* src = w + (size_t)co * 4608 + t * 18;
  unsigned int* op = (unsigned int*)o;
  #pragma unroll
  for (int k = 0; k < 9; ++k){
    unsigned short lo = f2bf(src[k]);
    unsigned short hi = f2bf(src[9 + k]);
    op[((size_t)k * 256 + co) * 256 + t] = lo | ((unsigned int)hi << 16);
  }
}
__global__ __launch_bounds__(256)
void prep_wfus_k(const float* __restrict__ w, unsigned short* __restrict__ o)
{
  int co = blockIdx.x, t = threadIdx.x;
  const float* src = w + (size_t)co * 4617 + t * 18;
  unsigned int* op = (unsigned int*)o;
  #pragma unroll
  for (int k = 0; k < 9; ++k){
    unsigned short lo = f2bf(src[k]);
    unsigned short hi = f2bf(src[9 + k]);
    op[((size_t)k * 256 + co) * 288 + t] = lo | ((unsigned int)hi << 16);
  }
  if (t < 32){
    #pragma unroll
    for (int k = 0; k < 9; ++k){
      unsigned int val = 0;
      if (t == 0) val = (unsigned int)f2bf(w[(size_t)co * 4617 + 512 * 9 + k]);
      op[((size_t)k * 256 + co) * 288 + 256 + t] = val;
    }
  }
}
__global__ __launch_bounds__(256)
void prep_wsr_k(const float* __restrict__ w, unsigned short* __restrict__ o)
{
  __shared__ float ld[64][65];
  int co = blockIdx.x;
  int t = threadIdx.x;
  for (int cib = 0; cib < 256; cib += 64){
    int cil = t >> 2, tq = t & 3;
    const float* src = w + ((size_t)co * 256 + cib + cil) * 64 + tq * 16;
    float v[16];
    #pragma unroll
    for (int k = 0; k < 16; ++k) v[k] = src[k];
    __syncthreads();
    #pragma unroll
    for (int k = 0; k < 16; ++k) ld[cil][tq * 16 + k] = v[k];
    __syncthreads();
    #pragma unroll
    for (int tp = 0; tp < 16; ++tp){
      int tap = tp * 4 + (t >> 6);
      int ci = t & 63;
      o[((size_t)tap * 256 + co) * 256 + cib + ci] = f2bf(ld[ci][tap]);
    }
  }
}
__global__ __launch_bounds__(256)
void tranw_k(const float* __restrict__ in, unsigned short* __restrict__ out, int R, int C)
{
  __shared__ float tl[32][33];
  int tiles_c = C >> 5;
  int tr = (blockIdx.x / tiles_c) << 5, tc = (blockIdx.x % tiles_c) << 5;
  int t = threadIdx.x; int r = t >> 5, c = t & 31;
  #pragma unroll
  for (int p = 0; p < 4; ++p)
    tl[r + p * 8][c] = in[(size_t)(tr + r + p * 8) * C + tc + c];
  __syncthreads();
  #pragma unroll
  for (int p = 0; p < 4; ++p)
    out[(size_t)(tc + r + p * 8) * R + tr + c] = f2bf(tl[c][r + p * 8]);
}
__global__ __launch_bounds__(256)
void wqprep_k(const float* __restrict__ w, unsigned short* __restrict__ o)
{
  int co = blockIdx.x, t = threadIdx.x;
  int c = t >> 3, e = t & 7;
  o[co * 256 + ((c ^ (co & 7)) * 8) + e] = f2bf(w[co * 256 + t]);
}

// ---------------------------------------------------------------- GEMM params
struct GemmP {
  const unsigned short* A;
  const unsigned short* W;
  const float* ep_scale;
  const float* ep_shift;
  void* out;
  int img_px, row_px, px_el, ch_off, y0, x0;
  int tapw, stridepix, out_w, out_imgpx;
  int Cin, Mtot, Mtiles, Ntiles, k_per;
};

// ---------------------------------------------------------------- merged SR conv GEMM (f32 partials)
__global__ __launch_bounds__(256)
void gemm_sr_k(GemmP pa, GemmP pb, float* __restrict__ outA, float* __restrict__ outB)
{
  const int t = threadIdx.x;
  const int lane = t & 63;
  const int wid = t >> 6;
  const int wr = wid >> 1, wc = wid & 1;

  const int cpx = gridDim.x >> 3;
  int pid = (blockIdx.x & 7) * cpx + (blockIdx.x >> 3);
  const int side = pid >= 128;
  const GemmP& p = side ? pb : pa;
  float* outp = side ? outB : outA;
  pid &= 127;

  __shared__ __bf16 As[2][128 * 64];
  __shared__ __bf16 Bs[2][128 * 64];

  const int mn = p.Mtiles * p.Ntiles;   // 16
  int within = pid % mn;
  int slot = pid / mn;                  // 0..7
  int mt = within / p.Ntiles;
  int nt = within - mt * p.Ntiles;
  int kb = slot * p.k_per;
  int tap0 = kb / p.Cin;
  int ntap = p.k_per / p.Cin;           // 8

  long long apix[4]; int cbg8[4]; int wrow[4];
  #pragma unroll
  for (int i = 0; i < 4; ++i){
    int r = i * 32 + (t >> 3);
    cbg8[i] = ((t & 7) ^ (r & 7)) * 8;
    int n = mt * 128 + r;
    int nc = n < p.Mtot ? n : 0;
    int b = nc / p.out_imgpx; int rr = nc - b * p.out_imgpx;
    int yo = rr / p.out_w;    int xo = rr - yo * p.out_w;
    apix[i] = (long long)b * p.img_px + (long long)(yo * p.stridepix + p.y0) * p.row_px
            + (xo * p.stridepix + p.x0);
    wrow[i] = (nt * 128 + r) * p.Cin + cbg8[i];
  }

  f32x4 acc[4][4];
  #pragma unroll
  for (int i = 0; i < 4; ++i)
    #pragma unroll
    for (int j = 0; j < 4; ++j)
      acc[i][j] = f32x4{0.f, 0.f, 0.f, 0.f};

  const long long wstap = 256LL * p.Cin;

  auto STAGE = [&](int buf, int tap, int cib){
    int dy = tap / p.tapw, dx = tap - dy * p.tapw;
    const unsigned short* wb = p.W + (long long)tap * wstap + cib;
    const long long aoff = (long long)(dy * p.row_px + dx) * p.px_el + p.ch_off + cib;
    #pragma unroll
    for (int i = 0; i < 4; ++i){
      __builtin_amdgcn_global_load_lds(
          (AS1 void*)(p.A + apix[i] * p.px_el + aoff + cbg8[i]),
          (AS3 void*)(&As[buf][i * 2048 + wid * 512]),
          16, 0, 0);
      __builtin_amdgcn_global_load_lds(
          (AS1 void*)(wb + wrow[i]),
          (AS3 void*)(&Bs[buf][i * 2048 + wid * 512]),
          16, 0, 0);
    }
  };

  const int NT = (p.Cin >> 6) * ntap;
  STAGE(0, tap0, 0);
  int tpn = 1, tap_n = tap0 + 1, cib_n = 0;
  int cur = 0;

  for (int kt = 0; kt < NT; ++kt){
    if (kt + 1 < NT){
      STAGE(cur ^ 1, tap_n, cib_n);
      ++tpn; ++tap_n;
      if (tpn == ntap){ tpn = 0; tap_n = tap0; cib_n += 64; }
      asm volatile("s_waitcnt vmcnt(8)" ::: "memory");
    } else {
      asm volatile("s_waitcnt vmcnt(0)" ::: "memory");
    }
    __builtin_amdgcn_s_barrier();
    __builtin_amdgcn_sched_barrier(0);

    #pragma unroll
    for (int ks = 0; ks < 2; ++ks){
      bf16x8 av[4], bv[4];
      #pragma unroll
      for (int mi = 0; mi < 4; ++mi){
        int ar = wr * 64 + mi * 16 + (lane & 15);
        int cb = (ks * 4 + (lane >> 4)) ^ (ar & 7);
        av[mi] = *reinterpret_cast<const bf16x8*>(&As[cur][ar * 64 + cb * 8]);
      }
      #pragma unroll
      for (int ni = 0; ni < 4; ++ni){
        int br = wc * 64 + ni * 16 + (lane & 15);
        int cb = (ks * 4 + (lane >> 4)) ^ (br & 7);
        bv[ni] = *reinterpret_cast<const bf16x8*>(&Bs[cur][br * 64 + cb * 8]);
      }
      #pragma unroll
      for (int mi = 0; mi < 4; ++mi)
        #pragma unroll
        for (int ni = 0; ni < 4; ++ni)
          acc[mi][ni] = __builtin_amdgcn_mfma_f32_16x16x32_bf16(av[mi], bv[ni], acc[mi][ni], 0, 0, 0);
    }

    __builtin_amdgcn_sched_barrier(0);
    __builtin_amdgcn_s_barrier();
    cur ^= 1;
  }

  const int r0 = (lane >> 4) * 4;
  const int c0 = lane & 15;
  #pragma unroll
  for (int mi = 0; mi < 4; ++mi){
    int nbase = mt * 128 + wr * 64 + mi * 16 + r0;
    #pragma unroll
    for (int ni = 0; ni < 4; ++ni){
      int co = nt * 128 + wc * 64 + ni * 16 + c0;
      f32x4 a = acc[mi][ni];
      float* o = outp + (size_t)slot * 968 * 256;
      #pragma unroll
      for (int r = 0; r < 4; ++r){
        int n = nbase + r;
        if (n < p.Mtot) o[(size_t)n * 256 + co] = a[r];
      }
    }
  }
}

// ---------------------------------------------------------------- 256^2 8-phase GEMM (big convs, R9 schedule + R12 STG placement)
// Phase 0: STG pair0 + vmcnt(2); ph1: pair1; ph2: pairs 2 AND 3; ph3: none.
template<int EPI>   // 0: BN+ReLU -> bf16 NHWC[.][256]   1: BN+ReLU -> f32 NCHW
__global__ __launch_bounds__(512, 2)
void gemm256_k(GemmP p)
{
  __shared__ __bf16 As[2][256 * 64];
  __shared__ __bf16 Bs[2][256 * 64];
  const int t = threadIdx.x;
  const int lane = t & 63;
  const int w = t >> 6;
  const int wr = w >> 2, wc = w & 3;
  const int c15 = lane & 15;
  const int h = lane >> 4;

  // bijective chunked XCD swizzle (m204)
  const int nwg = gridDim.x;
  const int q = nwg >> 3, r8 = nwg & 7;
  const int bid = blockIdx.x;
  const int xcd = bid & 7;
  const int mt = (xcd < r8 ? xcd * (q + 1) : r8 * (q + 1) + (xcd - r8) * q) + (bid >> 3);

  long long apixel[4];
  const unsigned short* wsrc[4];
  int lbase[4];
  #pragma unroll
  for (int i = 0; i < 4; ++i){
    int r = i * 64 + (t >> 3);
    int cb = ((t & 7) ^ (r & 7)) * 8;
    int n = mt * 256 + r;                   // Mtot = 242*256 exactly
    int b = n / p.out_imgpx; int rr = n - b * p.out_imgpx;
    int yo = rr / p.out_w;   int xo = rr - yo * p.out_w;
    long long pix = (long long)b * p.img_px + (long long)(yo * p.stridepix + p.y0) * p.row_px
                  + (xo * p.stridepix + p.x0);
    apixel[i] = pix * p.px_el + p.ch_off + cb;
    wsrc[i] = p.W + (long long)r * p.Cin + cb;
    lbase[i] = i * 4096 + w * 512;
  }

  f32x4 acc[8][4];
  #pragma unroll
  for (int i = 0; i < 8; ++i)
    #pragma unroll
    for (int j = 0; j < 4; ++j)
      acc[i][j] = f32x4{0.f, 0.f, 0.f, 0.f};

  const long long wstap = 256LL * p.Cin;
  const int ntap = p.k_per / p.Cin;         // 9
  const int NT = (p.Cin >> 6) * ntap;       // 72 or 81

  auto STG = [&](int buf, int i, long long aoff, long long woff){
    __builtin_amdgcn_global_load_lds(
        (AS1 void*)(p.A + apixel[i] + aoff),
        (AS3 void*)(&As[buf][lbase[i]]), 16, 0, 0);
    __builtin_amdgcn_global_load_lds(
        (AS1 void*)(wsrc[i] + woff),
        (AS3 void*)(&Bs[buf][lbase[i]]), 16, 0, 0);
  };
  auto LDA = [&](bf16x8* av, int mi0, int ks, int buf){
    #pragma unroll
    for (int m = 0; m < 4; ++m){
      int ar = wr * 128 + (mi0 + m) * 16 + c15;
      int cb = (ks * 4 + h) ^ (ar & 7);
      av[m] = *reinterpret_cast<const bf16x8*>(&As[buf][ar * 64 + cb * 8]);
    }
  };
  auto LDB = [&](bf16x8* bv, int ks, int buf){
    #pragma unroll
    for (int n = 0; n < 4; ++n){
      int br = wc * 64 + n * 16 + c15;
      int cb = (ks * 4 + h) ^ (br & 7);
      bv[n] = *reinterpret_cast<const bf16x8*>(&Bs[buf][br * 64 + cb * 8]);
    }
  };
  auto MM = [&](bf16x8* av, bf16x8* bv, int mi0){
    __builtin_amdgcn_s_setprio(1);
    #pragma unroll
    for (int m = 0; m < 4; ++m)
      #pragma unroll
      for (int n = 0; n < 4; ++n)
        acc[mi0 + m][n] = __builtin_amdgcn_mfma_f32_16x16x32_bf16(av[m], bv[n], acc[mi0 + m][n], 0, 0, 0);
    __builtin_amdgcn_s_setprio(0);
  };

  // prologue: stage kt=0 fully
  #pragma unroll
  for (int i = 0; i < 4; ++i) STG(0, i, 0, 0);

  int tap_n = 1, cib_n = 0;
  int cur = 0;

  for (int kt = 0; kt < NT; ++kt){
    const bool last = (kt == NT - 1);
    long long aoff_n = 0, woff_n = 0;
    if (!last){
      int dy = tap_n / p.tapw, dx = tap_n - dy * p.tapw;
      aoff_n = (long long)(dy * p.row_px + dx) * p.px_el + cib_n;
      woff_n = (long long)tap_n * wstap + cib_n;
    }
    bf16x8 av[4], bv[4];

    // ---- phase 0 ----
    if (!last){
      STG(cur ^ 1, 0, aoff_n, woff_n);
      asm volatile("s_waitcnt vmcnt(2)" ::: "memory");   // kt's 8 landed; kt+1 pair0 in flight
    } else {
      asm volatile("s_waitcnt vmcnt(0)" ::: "memory");
    }
    BARRIER();
    LDA(av, 0, 0, cur); LDB(bv, 0, cur);
    MM(av, bv, 0);
    BARRIER();
    // ---- phase 1 ----
    LDA(av, 4, 0, cur);
    if (!last) STG(cur ^ 1, 1, aoff_n, woff_n);
    BARRIER();
    MM(av, bv, 4);
    BARRIER();
    // ---- phase 2: pairs 2 AND 3 (R12: last pair gets >=2 phases of slack) ----
    LDA(av, 0, 1, cur); LDB(bv, 1, cur);
    if (!last){
      STG(cur ^ 1, 2, aoff_n, woff_n);
      STG(cur ^ 1, 3, aoff_n, woff_n);
    }
    BARRIER();
    MM(av, bv, 0);
    BARRIER();
    // ---- phase 3 ----
    LDA(av, 4, 1, cur);
    BARRIER();
    MM(av, bv, 4);
    BARRIER();

    cur ^= 1;
    if (!last){ ++tap_n; if (tap_n == ntap){ tap_n = 0; cib_n += 64; } }
  }

  // ---- epilogue ----
  const int r0 = (lane >> 4) * 4;
  #pragma unroll
  for (int mi = 0; mi < 8; ++mi){
    int nbase = mt * 256 + wr * 128 + mi * 16 + r0;
    #pragma unroll
    for (int ni = 0; ni < 4; ++ni){
      int co = wc * 64 + ni * 16 + c15;
      f32x4 a = acc[mi][ni];
      if constexpr (EPI == 0){
        float sc = p.ep_scale[co], sh = p.ep_shift[co];
        unsigned short* o = (unsigned short*)p.out;
        #pragma unroll
        for (int r = 0; r < 4; ++r){
          float v = fmaf(a[r], sc, sh); v = v > 0.f ? v : 0.f;
          o[(size_t)(nbase + r) * 256 + co] = f2bf(v);
        }
      } else {
        float sc = p.ep_scale[co], sh = p.ep_shift[co];
        float* o = (float*)p.out;
        int b = nbase / 7744; int s = nbase - b * 7744;
        float4 v;
        v.x = fmaxf(fmaf(a[0], sc, sh), 0.f);
        v.y = fmaxf(fmaf(a[1], sc, sh), 0.f);
        v.z = fmaxf(fmaf(a[2], sc, sh), 0.f);
        v.w = fmaxf(fmaf(a[3], sc, sh), 0.f);
        *reinterpret_cast<float4*>(o + ((size_t)(b * 256 + co)) * 7744 + s) = v;
      }
    }
  }
}

// ---------------------------------------------------------------- spatial mask
__global__ __launch_bounds__(256)
void mask_k(const unsigned short* __restrict__ h1, const float* __restrict__ w2,
            const float* __restrict__ b2, float* __restrict__ mask,
            unsigned short* __restrict__ FusPad)
{
  __shared__ float w[256];
  int t = threadIdx.x;
  w[t] = w2[t];
  __syncthreads();
  int n = blockIdx.x * 256 + t;
  const unsigned short* row = h1 + (size_t)n * 256;
  float s = b2[0];
  for (int c = 0; c < 256; c += 8){
    union { uint4 v; unsigned short s_[8]; } u;
    u.v = *reinterpret_cast<const uint4*>(row + c);
    #pragma unroll
    for (int j = 0; j < 8; ++j) s = fmaf(bf2f(u.s_[j]), w[c + j], s);
  }
  float m = 1.f / (1.f + __expf(-s));
  mask[n] = m;
  int b = n / 7744, sr = n - b * 7744;
  int y = sr / 88, x = sr - y * 88;
  FusPad[(((size_t)b * 90 + y + 1) * 90 + (x + 1)) * 576 + 512] = f2bf(m);
}

// ---------------------------------------------------------------- f_depth * mask -> NHWC bf16
__global__ __launch_bounds__(256)
void fdm_k(const unsigned short* __restrict__ Xpad, const float* __restrict__ mask,
           unsigned short* __restrict__ fdm)
{
  int idx = blockIdx.x * 256 + threadIdx.x;
  int n = idx >> 5, cb = idx & 31;
  int b = n / 7744, s = n - b * 7744;
  int y = s / 88, x = s - y * 88;
  size_t pix = ((size_t)(b * 90 + y + 1)) * 90 + x + 1;
  union { uint4 v; unsigned short s_[8]; } u, w;
  u.v = *reinterpret_cast<const uint4*>(Xpad + pix * 512 + 256 + cb * 8);
  float m = mask[n];
  #pragma unroll
  for (int j = 0; j < 8; ++j) w.s_[j] = f2bf(bf2f(u.s_[j]) * m);
  *reinterpret_cast<uint4*>(fdm + (size_t)n * 256 + cb * 8) = w.v;
}

// ---------------------------------------------------------------- merged split-K sum + channel LN (both sides)
__global__ __launch_bounds__(256)
void lnkvr2_k(const float* __restrict__ partA, const float* __restrict__ partB,
              const float* __restrict__ srbA, const float* __restrict__ srbB,
              const float* __restrict__ lngA, const float* __restrict__ lngB,
              const float* __restrict__ lnbA, const float* __restrict__ lnbB,
              unsigned short* __restrict__ kvrA, unsigned short* __restrict__ kvrB)
{
  int n = blockIdx.x, t = threadIdx.x;
  int side = n >= 968; n -= side * 968;
  const float* part = side ? partB : partA;
  const float* srb = side ? srbB : srbA;
  const float* lng = side ? lngB : lngA;
  const float* lnb = side ? lnbB : lnbA;
  unsigned short* kvr = side ? kvrB : kvrA;

  float v = srb[t];
  for (int s = 0; s < 8; ++s) v += part[((size_t)s * 968 + n) * 256 + t];
  float s1 = v, s2 = v * v;
  #pragma unroll
  for (int o = 1; o < 64; o <<= 1){ s1 += __shfl_xor(s1, o, 64); s2 += __shfl_xor(s2, o, 64); }
  __shared__ float a1[4], a2[4];
  if ((t & 63) == 0){ a1[t >> 6] = s1; a2[t >> 6] = s2; }
  __syncthreads();
  float t1 = a1[0] + a1[1] + a1[2] + a1[3];
  float t2 = a2[0] + a2[1] + a2[2] + a2[3];
  float mean = t1 * (1.f / 256.f);
  float var = t2 * (1.f / 256.f) - mean * mean;
  float rstd = rsqrtf(var + 1e-5f);
  kvr[(size_t)n * 256 + t] = f2bf((v - mean) * rstd * lng[t] + lnb[t]);
}

// ---------------------------------------------------------------- merged V-conv (+ K-proj) both sides
__global__ __launch_bounds__(256)
void vconv2_k(const unsigned short* __restrict__ kvrA, const unsigned short* __restrict__ kvrB,
              const unsigned short* __restrict__ vwtA, const unsigned short* __restrict__ vwtB,
              const float* __restrict__ vbA, const float* __restrict__ vbB,
              const unsigned short* __restrict__ kwtA, const unsigned short* __restrict__ kwtB,
              const float* __restrict__ kbA, const float* __restrict__ kbB,
              unsigned short* __restrict__ VBtA, unsigned short* __restrict__ VBtB,
              float* __restrict__ KBA, float* __restrict__ KBB)
{
  int n = blockIdx.x;
  int side = n >= 968; n -= side * 968;
  const unsigned short* kvr = side ? kvrB : kvrA;
  const unsigned short* vwt = side ? vwtB : vwtA;
  const float* vb = side ? vbB : vbA;
  const unsigned short* kwt = side ? kwtB : kwtA;
  const float* kbias = side ? kbB : kbA;
  unsigned short* VBt = side ? VBtB : VBtA;
  float* KB = side ? KBB : KBA;

  __shared__ float rowf[256];
  const int t = threadIdx.x;
  rowf[t] = bf2f(kvr[(size_t)n * 256 + t]);
  __syncthreads();
  float sum = vb[t];
  #pragma unroll 8
  for (int c = 0; c < 256; ++c)
    sum = fmaf(rowf[c], bf2f(vwt[(size_t)c * 256 + t]), sum);
  int b = n / 121, m = n - b * 121;
  VBt[(size_t)b * 32768 + (size_t)t * 128 + m] = f2bf(sum);

  if (t < 32){
    float ks = kbias[t];
    #pragma unroll 8
    for (int c = 0; c < 256; ++c)
      ks = fmaf(rowf[c], bf2f(kwt[c * 32 + t]), ks);
    KB[(size_t)n * 32 + t] = ks;
  }
}

// ---------------------------------------------------------------- merged MFMA attention (+fused Q-proj) + LN + residual
struct AttnS {
  const unsigned short* Qsrc;
  const unsigned short* wq;
  const float* qb;
  const float* Kbuf;
  const unsigned short* VBt;
  const float* ng;
  const float* nb;
  const float* gm;
  int qmode, resOff, outOff;
};

__global__ __launch_bounds__(512, 2)
void attn2_k(AttnS s0, AttnS s1,
             const unsigned short* __restrict__ Xpad,
             unsigned short* __restrict__ FusPad)
{
  __shared__ unsigned short Vt[2][256][64];
  __shared__ unsigned short Pl[2][128][64];
  __shared__ unsigned short Qs[128][64];
  __shared__ unsigned short Ks[128][64];
  __shared__ unsigned short Wqs[32][256];

  int bid = blockIdx.x;
  const int side = bid >= 488;
  bid -= side * 488;
  const AttnS& s = side ? s1 : s0;

  const int t = threadIdx.x;
  const int lane = t & 63;
  const int w = t >> 6;
  const int c15 = lane & 15;
  const int h = lane >> 4;

  const int b = bid / 61;
  const int rb = bid - b * 61;
  const int nb0 = rb * 128;

  const unsigned short* vsrc = s.VBt + (size_t)b * 32768;
  #pragma unroll
  for (int kt = 0; kt < 2; ++kt)
    #pragma unroll
    for (int i = 0; i < 4; ++i){
      int rowbase = i * 64 + w * 8;
      int c = rowbase + (lane >> 3);
      int mchunk = (lane & 7) ^ (c & 7);
      __builtin_amdgcn_global_load_lds(
        (AS1 void*)(vsrc + (size_t)c * 128 + kt * 64 + mchunk * 8),
        (AS3 void*)(&Vt[kt][rowbase][0]),
        16, 0, 0);
    }

  {
    uint4* d = (uint4*)&Wqs[0][0]; const uint4* sw = (const uint4*)s.wq;
    d[t] = sw[t];
    d[t + 512] = sw[t + 512];
  }
  {
    int m = t >> 2, part = t & 3;
    union { uint4 v; unsigned short s_[8]; } u;
    u.v = uint4{0, 0, 0, 0};
    if (m < 121){
      const float* kp = s.Kbuf + ((size_t)b * 121 + m) * 32 + part * 8;
      float4 a = *reinterpret_cast<const float4*>(kp);
      float4 bb = *reinterpret_cast<const float4*>(kp + 4);
      u.s_[0] = f2bf(a.x); u.s_[1] = f2bf(a.y); u.s_[2] = f2bf(a.z); u.s_[3] = f2bf(a.w);
      u.s_[4] = f2bf(bb.x); u.s_[5] = f2bf(bb.y); u.s_[6] = f2bf(bb.z); u.s_[7] = f2bf(bb.w);
    }
    *reinterpret_cast<uint4*>(&Ks[m][(part ^ (m & 7)) * 8]) = u.v;
  }
  __syncthreads();

  const int nA = w * 16 + c15;
  const float scale = 0.17677669529663687f;  // 32^-0.5

  {
    int gn = nb0 + nA; if (gn > 7743) gn = 7743;
    const unsigned short* xrow;
    if (s.qmode){
      int y = gn / 88, x = gn - y * 88;
      xrow = s.Qsrc + (((size_t)(b * 90) + y + 1) * 90 + (x + 1)) * 512;
    } else {
      xrow = s.Qsrc + ((size_t)b * 7744 + gn) * 256;
    }
    f32x4 qacc[2];
    qacc[0] = f32x4{0.f, 0.f, 0.f, 0.f};
    qacc[1] = f32x4{0.f, 0.f, 0.f, 0.f};
    #pragma unroll
    for (int kt = 0; kt < 8; ++kt){
      bf16x8 ax = *reinterpret_cast<const bf16x8*>(xrow + kt * 32 + h * 8);
      #pragma unroll
      for (int ni = 0; ni < 2; ++ni){
        int co = ni * 16 + c15;
        bf16x8 bw = *reinterpret_cast<const bf16x8*>(&Wqs[co][((kt * 4 + h) ^ (co & 7)) * 8]);
        qacc[ni] = __builtin_amdgcn_mfma_f32_16x16x32_bf16(ax, bw, qacc[ni], 0, 0, 0);
      }
    }
    #pragma unroll
    for (int ni = 0; ni < 2; ++ni){
      int co = ni * 16 + c15;
      float bq = s.qb[co];
      #pragma unroll
      for (int r = 0; r < 4; ++r){
        int n = w * 16 + 4 * h + r;
        int chunk = (co >> 3) ^ (n & 7);
        Qs[n][chunk * 8 + (co & 7)] = f2bf((qacc[ni][r] + bq) * scale);
      }
    }
  }

  bf16x8 aq = *reinterpret_cast<const bf16x8*>(&Qs[nA][(h ^ (nA & 7)) * 8]);
  f32x4 sv[8];
  #pragma unroll
  for (int ni = 0; ni < 8; ++ni){
    int mrow = ni * 16 + c15;
    bf16x8 bk = *reinterpret_cast<const bf16x8*>(&Ks[mrow][(h ^ (mrow & 7)) * 8]);
    sv[ni] = __builtin_amdgcn_mfma_f32_16x16x32_bf16(aq, bk, f32x4{0.f,0.f,0.f,0.f}, 0, 0, 0);
  }
  if (c15 >= 9) sv[7] = f32x4{-1e30f, -1e30f, -1e30f, -1e30f};

  float rden[4];
  #pragma unroll
  for (int r = 0; r < 4; ++r){
    float mx = sv[0][r];
    #pragma unroll
    for (int ni = 1; ni < 8; ++ni) mx = fmaxf(mx, sv[ni][r]);
    #pragma unroll
    for (int o = 1; o < 16; o <<= 1) mx = fmaxf(mx, __shfl_xor(mx, o, 64));
    float sm = 0.f;
    #pragma unroll
    for (int ni = 0; ni < 8; ++ni){
      float p = __expf(sv[ni][r] - mx);
      sv[ni][r] = p;
      sm += p;
    }
    #pragma unroll
    for (int o = 1; o < 16; o <<= 1) sm += __shfl_xor(sm, o, 64);
    rden[r] = 1.f / sm;
  }
  #pragma unroll
  for (int ni = 0; ni < 8; ++ni){
    int m = ni * 16 + c15;
    int kt = m >> 6;
    int mq = (m & 63) >> 3;
    #pragma unroll
    for (int r = 0; r < 4; ++r){
      int n = w * 16 + 4 * h + r;
      Pl[kt][n][(mq ^ (n & 7)) * 8 + (m & 7)] = f2bf(sv[ni][r] * rden[r]);
    }
  }

  bf16x8 pa[2][2];
  #pragma unroll
  for (int kt = 0; kt < 2; ++kt)
    #pragma unroll
    for (int ks = 0; ks < 2; ++ks)
      pa[kt][ks] = *reinterpret_cast<const bf16x8*>(&Pl[kt][nA][((ks * 4 + h) ^ (nA & 7)) * 8]);

  f32x4 acc[16];
  #pragma unroll
  for (int ni = 0; ni < 16; ++ni) acc[ni] = f32x4{0.f, 0.f, 0.f, 0.f};
  #pragma unroll
  for (int ni = 0; ni < 16; ++ni){
    int crow = ni * 16 + c15;
    #pragma unroll
    for (int kt = 0; kt < 2; ++kt)
      #pragma unroll
      for (int ks = 0; ks < 2; ++ks){
        bf16x8 bv = *reinterpret_cast<const bf16x8*>(&Vt[kt][crow][((ks * 4 + h) ^ (crow & 7)) * 8]);
        acc[ni] = __builtin_amdgcn_mfma_f32_16x16x32_bf16(pa[kt][ks], bv, acc[ni], 0, 0, 0);
      }
  }

  float ngv[16], nbb[16];
  #pragma unroll
  for (int ni = 0; ni < 16; ++ni){
    int c = ni * 16 + c15;
    ngv[ni] = s.ng[c]; nbb[ni] = s.nb[c];
  }
  float g = s.gm[0]; g = fminf(fmaxf(g, 0.f), 1.f);

  #pragma unroll
  for (int r = 0; r < 4; ++r){
    float s1 = 0.f, s2 = 0.f;
    #pragma unroll
    for (int ni = 0; ni < 16; ++ni){ float v = acc[ni][r]; s1 += v; s2 += v * v; }
    #pragma unroll
    for (int o = 1; o < 16; o <<= 1){ s1 += __shfl_xor(s1, o, 64); s2 += __shfl_xor(s2, o, 64); }
    float mean = s1 * (1.f / 256.f);
    float var = s2 * (1.f / 256.f) - mean * mean;
    float rstd = rsqrtf(var + 1e-5f);

    int nloc = w * 16 + 4 * h + r;
    int rix = nb0 + nloc;
    if (rix < 7744){
      int y = rix / 88, x = rix - y * 88;
      size_t pix = ((size_t)(b * 90) + y + 1) * 90 + (x + 1);
      const unsigned short* res = Xpad + pix * 512 + s.resOff;
      unsigned short* outp = FusPad + pix * 576 + s.outOff;
      #pragma unroll
      for (int ni = 0; ni < 16; ++ni){
        int c = ni * 16 + c15;
        float yv = (acc[ni][r] - mean) * rstd * ngv[ni] + nbb[ni];
        outp[c] = f2bf(bf2f(res[c]) + g * yv);
      }
    }
  }
}

// ================================================================ host
extern "C" void kernel_launch(void* const* d_in, const int* in_sizes, int n_in,
                              void* d_out, int out_size, void* d_ws, size_t ws_size,
                              hipStream_t stream)
{
  const float* P[42];
  for (int i = 0; i < 42; ++i) P[i] = (const float*)d_in[i];

  char* ws = (char*)d_ws;
  size_t off = 0;
  auto take = [&](size_t bytes) -> char* {
    char* p = ws + off; off += (bytes + 255) & ~(size_t)255; return p;
  };
  unsigned short* XPAD = (unsigned short*)take(8ull * 8100 * 512 * 2);   // 66.4 MB
  unsigned short* FUSP = (unsigned short*)take(8ull * 8100 * 576 * 2);   // 74.6 MB
  unsigned short* H1   = (unsigned short*)take(61952ull * 256 * 2);      // 31.7 MB
  unsigned short* FDM  = H1;  // alias: h1 dead after mask_k
  unsigned short* W1T  = (unsigned short*)take(9ull * 256 * 512 * 2);
  unsigned short* WFT  = (unsigned short*)take(9ull * 256 * 576 * 2);
  unsigned short* WSRA = (unsigned short*)take(64ull * 256 * 256 * 2);
  unsigned short* WSRB = (unsigned short*)take(64ull * 256 * 256 * 2);
  float* PARTA = (float*)take(8ull * 968 * 256 * 4);
  float* PARTB = (float*)take(8ull * 968 * 256 * 4);
  unsigned short* KVRA = (unsigned short*)take(968ull * 256 * 2);
  unsigned short* KVRB = (unsigned short*)take(968ull * 256 * 2);
  float* KBA  = (float*)take(968ull * 32 * 4);
  float* KBB  = (float*)take(968ull * 32 * 4);
  unsigned short* VBTA = (unsigned short*)take(2ull * 8 * 256 * 128 * 2);
  unsigned short* VBTB = VBTA + 8ull * 256 * 128;
  float* MASK = (float*)take(61952ull * 4);
  float* SC1 = (float*)take(256 * 4);
  float* SH1 = (float*)take(256 * 4);
  float* SCF = (float*)take(256 * 4);
  float* SHF = (float*)take(256 * 4);
  unsigned short* WQSA = (unsigned short*)take(32ull * 256 * 2);
  unsigned short* WQSB = (unsigned short*)take(32ull * 256 * 2);
  unsigned short* KWTA = (unsigned short*)take(256ull * 32 * 2);
  unsigned short* VWTA = (unsigned short*)take(256ull * 256 * 2);
  unsigned short* KWTB = (unsigned short*)take(256ull * 32 * 2);
  unsigned short* VWTB = (unsigned short*)take(256ull * 256 * 2);
  (void)ws_size; (void)in_sizes; (void)n_in; (void)out_size;

  zero_border_k<<<8 * 356, 128, 0, stream>>>(XPAD, 512);
  zero_border_k<<<8 * 356, 128, 0, stream>>>(FUSP, 576);
  zero_fustail_k<<<1936, 256, 0, stream>>>(FUSP);
  hipMemsetAsync(VBTA, 0, 2ull * 8 * 256 * 128 * 2, stream);

  bnprep_k<<<1, 256, 0, stream>>>(P[4], P[5], P[6], P[7], P[3],
                                  P[38], P[39], P[40], P[41], P[37],
                                  SC1, SH1, SCF, SHF);
  prep_xpad_k<<<7744, 256, 0, stream>>>(P[0], P[1], XPAD);
  prep_w1t_k<<<256, 256, 0, stream>>>(P[2], W1T);
  prep_wfus_k<<<256, 256, 0, stream>>>(P[36], WFT);
  prep_wsr_k<<<256, 256, 0, stream>>>(P[16], WSRA);
  prep_wsr_k<<<256, 256, 0, stream>>>(P[28], WSRB);
  wqprep_k<<<32, 256, 0, stream>>>(P[10], WQSA);
  wqprep_k<<<32, 256, 0, stream>>>(P[22], WQSB);
  tranw_k<<<8, 256, 0, stream>>>(P[12], KWTA, 32, 256);
  tranw_k<<<64, 256, 0, stream>>>(P[14], VWTA, 256, 256);
  tranw_k<<<8, 256, 0, stream>>>(P[24], KWTB, 32, 256);
  tranw_k<<<64, 256, 0, stream>>>(P[26], VWTB, 256, 256);

  // conv1 3x3 (512->256) + BN + ReLU -> h1 NHWC bf16   [256^2 8-phase]
  GemmP g1{};
  g1.A = XPAD; g1.W = W1T; g1.ep_scale = SC1; g1.ep_shift = SH1; g1.out = H1;
  g1.img_px = 8100; g1.row_px = 90; g1.px_el = 512; g1.ch_off = 0; g1.y0 = 0; g1.x0 = 0;
  g1.tapw = 3; g1.stridepix = 1; g1.out_w = 88; g1.out_imgpx = 7744;
  g1.Cin = 512; g1.Mtot = 61952; g1.Mtiles = 242; g1.Ntiles = 1; g1.k_per = 4608;
  gemm256_k<0><<<242, 512, 0, stream>>>(g1);

  mask_k<<<242, 256, 0, stream>>>(H1, P[8], P[9], MASK, FUSP);
  fdm_k<<<7744, 256, 0, stream>>>(XPAD, MASK, FDM);

  // ---------------- merged SRA pipelines ----------------
  GemmP ga{};
  ga.A = FDM; ga.W = WSRA; ga.out = nullptr;
  ga.img_px = 7744; ga.row_px = 88; ga.px_el = 256; ga.ch_off = 0; ga.y0 = 0; ga.x0 = 0;
  ga.tapw = 8; ga.stridepix = 8; ga.out_w = 11; ga.out_imgpx = 121;
  ga.Cin = 256; ga.Mtot = 968; ga.Mtiles = 8; ga.Ntiles = 2; ga.k_per = 2048;
  GemmP gb = ga;
  gb.A = XPAD; gb.W = WSRB;
  gb.img_px = 8100; gb.row_px = 90; gb.px_el = 512; gb.y0 = 1; gb.x0 = 1;
  gemm_sr_k<<<256, 256, 0, stream>>>(ga, gb, PARTA, PARTB);

  lnkvr2_k<<<1936, 256, 0, stream>>>(PARTA, PARTB, P[17], P[29], P[18], P[30],
                                     P[19], P[31], KVRA, KVRB);
  vconv2_k<<<1936, 256, 0, stream>>>(KVRA, KVRB, VWTA, VWTB, P[15], P[27],
                                     KWTA, KWTB, P[13], P[25],
                                     VBTA, VBTB, KBA, KBB);

  AttnS s0{XPAD, WQSA, P[11], KBA, VBTA, P[20], P[21], P[34], 1, 0, 0};
  AttnS s1{FDM,  WQSB, P[23], KBB, VBTB, P[32], P[33], P[35], 0, 256, 256};
  attn2_k<<<976, 512, 0, stream>>>(s0, s1, XPAD, FUSP);

  // final fused conv 3x3 (576->256) + BN + ReLU -> d_out f32 NCHW   [256^2 8-phase]
  GemmP gf{};
  gf.A = FUSP; gf.W = WFT; gf.ep_scale = SCF; gf.ep_shift = SHF; gf.out = d_out;
  gf.img_px = 8100; gf.row_px = 90; gf.px_el = 576; gf.ch_off = 0; gf.y0 = 0; gf.x0 = 0;
  gf.tapw = 3; gf.stridepix = 1; gf.out_w = 88; gf.out_imgpx = 7744;
  gf.Cin = 576; gf.Mtot = 61952; gf.Mtiles = 242; gf.Ntiles = 1; gf.k_per = 5184;
  gemm256_k<1><<<242, 512, 0, stream>>>(gf);
}

// Round 13
// 531.982 us; speedup vs baseline: 1.0305x; 1.0305x over previous
//
#include <hip/hip_runtime.h>
#include <hip/hip_bf16.h>

// BiDirectionalFusionModule on MI355X.
// R2: global_load_lds(16B) GEMM staging; coalesced weight preps.
// R5: MFMA attention (8 waves, wave-local softmax/LN, swizzled LDS, V via lds-DMA).
// R6: GEMM L2-locality (cib-outer/tap-inner, XCD chunk swizzle): FETCH 574->60MB.
// R7: Q-proj fused into attn_k; targeted border/tail zeroing.
// R9: 8-phase 256^2 GEMM (T3+T4+T5): 186us/conv, MfmaUtil 38% (measured best).
// R10/R12: two schedule perturbations both regressed ~7% -> R9 phase layout is
//          a local optimum of this structure.
// R13: exact revert to R11 (measured best: 534.8us, absmax 0.0625).

typedef __bf16 bf16x8 __attribute__((ext_vector_type(8)));
typedef float f32x4 __attribute__((ext_vector_type(4)));

#define AS1 __attribute__((address_space(1)))
#define AS3 __attribute__((address_space(3)))
#define DEVI __device__ __forceinline__
#define BARRIER() do { asm volatile("" ::: "memory"); __builtin_amdgcn_s_barrier(); asm volatile("" ::: "memory"); } while (0)

DEVI float bf2f(unsigned short u){
  union { unsigned int i; float f; } v; v.i = ((unsigned int)u) << 16; return v.f;
}
DEVI unsigned short f2bf(float f){
  union { float f; unsigned int i; } v; v.f = f;
  unsigned int x = v.i;
  unsigned int r = (x + 0x7fffu + ((x >> 16) & 1u)) >> 16;
  return (unsigned short)r;
}

// ---------------------------------------------------------------- BN prep
__global__ void bnprep_k(const float* __restrict__ g1, const float* __restrict__ be1,
                         const float* __restrict__ m1, const float* __restrict__ v1,
                         const float* __restrict__ b1,
                         const float* __restrict__ gf, const float* __restrict__ bef,
                         const float* __restrict__ mf, const float* __restrict__ vf,
                         const float* __restrict__ bf,
                         float* __restrict__ sc1, float* __restrict__ sh1,
                         float* __restrict__ scf, float* __restrict__ shf)
{
  int c = threadIdx.x;
  float s = g1[c] * rsqrtf(v1[c] + 1e-5f);
  sc1[c] = s; sh1[c] = (b1[c] - m1[c]) * s + be1[c];
  s = gf[c] * rsqrtf(vf[c] + 1e-5f);
  scf[c] = s; shf[c] = (bf[c] - mf[c]) * s + bef[c];
}

// ---------------------------------------------------------------- targeted zeroing
__global__ __launch_bounds__(128)
void zero_border_k(unsigned short* __restrict__ buf, int px_el)
{
  int bi = blockIdx.x;
  int img = bi / 356, e = bi - img * 356;
  int y, x;
  if (e < 90){ y = 0; x = e; }
  else if (e < 180){ y = 89; x = e - 90; }
  else if (e < 268){ y = e - 180 + 1; x = 0; }
  else { y = e - 268 + 1; x = 89; }
  size_t pix = ((size_t)img * 90 + y) * 90 + x;
  int t = threadIdx.x;
  if (t < (px_el >> 3))
    *reinterpret_cast<uint4*>(buf + pix * px_el + t * 8) = uint4{0, 0, 0, 0};
}
__global__ __launch_bounds__(256)
void zero_fustail_k(unsigned short* __restrict__ FusPad)
{
  int idx = blockIdx.x * 256 + threadIdx.x;   // 61952*8
  int n = idx >> 3, ch = idx & 7;
  int b = n / 7744, s = n - b * 7744;
  int y = s / 88, x = s - y * 88;
  size_t pix = ((size_t)(b * 90 + y + 1)) * 90 + (x + 1);
  *reinterpret_cast<uint4*>(FusPad + pix * 576 + 512 + ch * 8) = uint4{0, 0, 0, 0};
}

// ------------------------------------------------- NCHW f32 -> padded NHWC bf16
__global__ __launch_bounds__(256)
void prep_xpad_k(const float* __restrict__ rgb, const float* __restrict__ dep,
                 unsigned short* __restrict__ Xpad)
{
  __shared__ unsigned short tile[64][65];
  int bi = blockIdx.x;
  int b = bi / 968;
  int rem = bi - b * 968;
  int cblk = rem / 121;
  int pblk = rem - cblk * 121;
  int t = threadIdx.x;
  int pl = t & 63;
  #pragma unroll
  for (int pass = 0; pass < 16; ++pass){
    int cl = pass * 4 + (t >> 6);
    int c = cblk * 64 + cl;
    const float* sp = (c < 256) ? (rgb + ((size_t)b * 256 + c) * 7744)
                                : (dep + ((size_t)b * 256 + (c - 256)) * 7744);
    tile[cl][pl] = f2bf(sp[pblk * 64 + pl]);
  }
  __syncthreads();
  int cl2 = t & 63;
  for (int pass = 0; pass < 16; ++pass){
    int pl2 = pass * 4 + (t >> 6);
    int pixg = pblk * 64 + pl2;
    int y = pixg / 88, x = pixg - y * 88;
    Xpad[(((size_t)b * 90 + y + 1) * 90 + (x + 1)) * 512 + cblk * 64 + cl2] = tile[cl2][pl2];
  }
}

// ---------------------------------------------------------------- weight reshuffles
__global__ __launch_bounds__(256)
void prep_w1t_k(const float* __restrict__ w, unsigned short* __restrict__ o)
{
  int co = blockIdx.x, t = threadIdx.x;
  const float* src = w + (size_t)co * 4608 + t * 18;
  unsigned int* op = (unsigned int*)o;
  #pragma unroll
  for (int k = 0; k < 9; ++k){
    unsigned short lo = f2bf(src[k]);
    unsigned short hi = f2bf(src[9 + k]);
    op[((size_t)k * 256 + co) * 256 + t] = lo | ((unsigned int)hi << 16);
  }
}
__global__ __launch_bounds__(256)
void prep_wfus_k(const float* __restrict__ w, unsigned short* __restrict__ o)
{
  int co = blockIdx.x, t = threadIdx.x;
  const float* src = w + (size_t)co * 4617 + t * 18;
  unsigned int* op = (unsigned int*)o;
  #pragma unroll
  for (int k = 0; k < 9; ++k){
    unsigned short lo = f2bf(src[k]);
    unsigned short hi = f2bf(src[9 + k]);
    op[((size_t)k * 256 + co) * 288 + t] = lo | ((unsigned int)hi << 16);
  }
  if (t < 32){
    #pragma unroll
    for (int k = 0; k < 9; ++k){
      unsigned int val = 0;
      if (t == 0) val = (unsigned int)f2bf(w[(size_t)co * 4617 + 512 * 9 + k]);
      op[((size_t)k * 256 + co) * 288 + 256 + t] = val;
    }
  }
}
__global__ __launch_bounds__(256)
void prep_wsr_k(const float* __restrict__ w, unsigned short* __restrict__ o)
{
  __shared__ float ld[64][65];
  int co = blockIdx.x;
  int t = threadIdx.x;
  for (int cib = 0; cib < 256; cib += 64){
    int cil = t >> 2, tq = t & 3;
    const float* src = w + ((size_t)co * 256 + cib + cil) * 64 + tq * 16;
    float v[16];
    #pragma unroll
    for (int k = 0; k < 16; ++k) v[k] = src[k];
    __syncthreads();
    #pragma unroll
    for (int k = 0; k < 16; ++k) ld[cil][tq * 16 + k] = v[k];
    __syncthreads();
    #pragma unroll
    for (int tp = 0; tp < 16; ++tp){
      int tap = tp * 4 + (t >> 6);
      int ci = t & 63;
      o[((size_t)tap * 256 + co) * 256 + cib + ci] = f2bf(ld[ci][tap]);
    }
  }
}
__global__ __launch_bounds__(256)
void tranw_k(const float* __restrict__ in, unsigned short* __restrict__ out, int R, int C)
{
  __shared__ float tl[32][33];
  int tiles_c = C >> 5;
  int tr = (blockIdx.x / tiles_c) << 5, tc = (blockIdx.x % tiles_c) << 5;
  int t = threadIdx.x; int r = t >> 5, c = t & 31;
  #pragma unroll
  for (int p = 0; p < 4; ++p)
    tl[r + p * 8][c] = in[(size_t)(tr + r + p * 8) * C + tc + c];
  __syncthreads();
  #pragma unroll
  for (int p = 0; p < 4; ++p)
    out[(size_t)(tc + r + p * 8) * R + tr + c] = f2bf(tl[c][r + p * 8]);
}
__global__ __launch_bounds__(256)
void wqprep_k(const float* __restrict__ w, unsigned short* __restrict__ o)
{
  int co = blockIdx.x, t = threadIdx.x;
  int c = t >> 3, e = t & 7;
  o[co * 256 + ((c ^ (co & 7)) * 8) + e] = f2bf(w[co * 256 + t]);
}

// ---------------------------------------------------------------- GEMM params
struct GemmP {
  const unsigned short* A;
  const unsigned short* W;
  const float* ep_scale;
  const float* ep_shift;
  void* out;
  int img_px, row_px, px_el, ch_off, y0, x0;
  int tapw, stridepix, out_w, out_imgpx;
  int Cin, Mtot, Mtiles, Ntiles, k_per;
};

// ---------------------------------------------------------------- merged SR conv GEMM (f32 partials)
__global__ __launch_bounds__(256)
void gemm_sr_k(GemmP pa, GemmP pb, float* __restrict__ outA, float* __restrict__ outB)
{
  const int t = threadIdx.x;
  const int lane = t & 63;
  const int wid = t >> 6;
  const int wr = wid >> 1, wc = wid & 1;

  const int cpx = gridDim.x >> 3;
  int pid = (blockIdx.x & 7) * cpx + (blockIdx.x >> 3);
  const int side = pid >= 128;
  const GemmP& p = side ? pb : pa;
  float* outp = side ? outB : outA;
  pid &= 127;

  __shared__ __bf16 As[2][128 * 64];
  __shared__ __bf16 Bs[2][128 * 64];

  const int mn = p.Mtiles * p.Ntiles;   // 16
  int within = pid % mn;
  int slot = pid / mn;                  // 0..7
  int mt = within / p.Ntiles;
  int nt = within - mt * p.Ntiles;
  int kb = slot * p.k_per;
  int tap0 = kb / p.Cin;
  int ntap = p.k_per / p.Cin;           // 8

  long long apix[4]; int cbg8[4]; int wrow[4];
  #pragma unroll
  for (int i = 0; i < 4; ++i){
    int r = i * 32 + (t >> 3);
    cbg8[i] = ((t & 7) ^ (r & 7)) * 8;
    int n = mt * 128 + r;
    int nc = n < p.Mtot ? n : 0;
    int b = nc / p.out_imgpx; int rr = nc - b * p.out_imgpx;
    int yo = rr / p.out_w;    int xo = rr - yo * p.out_w;
    apix[i] = (long long)b * p.img_px + (long long)(yo * p.stridepix + p.y0) * p.row_px
            + (xo * p.stridepix + p.x0);
    wrow[i] = (nt * 128 + r) * p.Cin + cbg8[i];
  }

  f32x4 acc[4][4];
  #pragma unroll
  for (int i = 0; i < 4; ++i)
    #pragma unroll
    for (int j = 0; j < 4; ++j)
      acc[i][j] = f32x4{0.f, 0.f, 0.f, 0.f};

  const long long wstap = 256LL * p.Cin;

  auto STAGE = [&](int buf, int tap, int cib){
    int dy = tap / p.tapw, dx = tap - dy * p.tapw;
    const unsigned short* wb = p.W + (long long)tap * wstap + cib;
    const long long aoff = (long long)(dy * p.row_px + dx) * p.px_el + p.ch_off + cib;
    #pragma unroll
    for (int i = 0; i < 4; ++i){
      __builtin_amdgcn_global_load_lds(
          (AS1 void*)(p.A + apix[i] * p.px_el + aoff + cbg8[i]),
          (AS3 void*)(&As[buf][i * 2048 + wid * 512]),
          16, 0, 0);
      __builtin_amdgcn_global_load_lds(
          (AS1 void*)(wb + wrow[i]),
          (AS3 void*)(&Bs[buf][i * 2048 + wid * 512]),
          16, 0, 0);
    }
  };

  const int NT = (p.Cin >> 6) * ntap;
  STAGE(0, tap0, 0);
  int tpn = 1, tap_n = tap0 + 1, cib_n = 0;
  int cur = 0;

  for (int kt = 0; kt < NT; ++kt){
    if (kt + 1 < NT){
      STAGE(cur ^ 1, tap_n, cib_n);
      ++tpn; ++tap_n;
      if (tpn == ntap){ tpn = 0; tap_n = tap0; cib_n += 64; }
      asm volatile("s_waitcnt vmcnt(8)" ::: "memory");
    } else {
      asm volatile("s_waitcnt vmcnt(0)" ::: "memory");
    }
    __builtin_amdgcn_s_barrier();
    __builtin_amdgcn_sched_barrier(0);

    #pragma unroll
    for (int ks = 0; ks < 2; ++ks){
      bf16x8 av[4], bv[4];
      #pragma unroll
      for (int mi = 0; mi < 4; ++mi){
        int ar = wr * 64 + mi * 16 + (lane & 15);
        int cb = (ks * 4 + (lane >> 4)) ^ (ar & 7);
        av[mi] = *reinterpret_cast<const bf16x8*>(&As[cur][ar * 64 + cb * 8]);
      }
      #pragma unroll
      for (int ni = 0; ni < 4; ++ni){
        int br = wc * 64 + ni * 16 + (lane & 15);
        int cb = (ks * 4 + (lane >> 4)) ^ (br & 7);
        bv[ni] = *reinterpret_cast<const bf16x8*>(&Bs[cur][br * 64 + cb * 8]);
      }
      #pragma unroll
      for (int mi = 0; mi < 4; ++mi)
        #pragma unroll
        for (int ni = 0; ni < 4; ++ni)
          acc[mi][ni] = __builtin_amdgcn_mfma_f32_16x16x32_bf16(av[mi], bv[ni], acc[mi][ni], 0, 0, 0);
    }

    __builtin_amdgcn_sched_barrier(0);
    __builtin_amdgcn_s_barrier();
    cur ^= 1;
  }

  const int r0 = (lane >> 4) * 4;
  const int c0 = lane & 15;
  #pragma unroll
  for (int mi = 0; mi < 4; ++mi){
    int nbase = mt * 128 + wr * 64 + mi * 16 + r0;
    #pragma unroll
    for (int ni = 0; ni < 4; ++ni){
      int co = nt * 128 + wc * 64 + ni * 16 + c0;
      f32x4 a = acc[mi][ni];
      float* o = outp + (size_t)slot * 968 * 256;
      #pragma unroll
      for (int r = 0; r < 4; ++r){
        int n = nbase + r;
        if (n < p.Mtot) o[(size_t)n * 256 + co] = a[r];
      }
    }
  }
}

// ---------------------------------------------------------------- 256^2 8-phase GEMM (big convs, R9 schedule)
// Phase p: [STG pair p (+vmcnt at p=0)] BARRIER; LDA/LDB; 16 MFMA (setprio); BARRIER.
template<int EPI>   // 0: BN+ReLU -> bf16 NHWC[.][256]   1: BN+ReLU -> f32 NCHW
__global__ __launch_bounds__(512, 2)
void gemm256_k(GemmP p)
{
  __shared__ __bf16 As[2][256 * 64];
  __shared__ __bf16 Bs[2][256 * 64];
  const int t = threadIdx.x;
  const int lane = t & 63;
  const int w = t >> 6;
  const int wr = w >> 2, wc = w & 3;
  const int c15 = lane & 15;
  const int h = lane >> 4;

  // bijective chunked XCD swizzle (m204)
  const int nwg = gridDim.x;
  const int q = nwg >> 3, r8 = nwg & 7;
  const int bid = blockIdx.x;
  const int xcd = bid & 7;
  const int mt = (xcd < r8 ? xcd * (q + 1) : r8 * (q + 1) + (xcd - r8) * q) + (bid >> 3);

  long long apixel[4];
  const unsigned short* wsrc[4];
  int lbase[4];
  #pragma unroll
  for (int i = 0; i < 4; ++i){
    int r = i * 64 + (t >> 3);
    int cb = ((t & 7) ^ (r & 7)) * 8;
    int n = mt * 256 + r;                   // Mtot = 242*256 exactly
    int b = n / p.out_imgpx; int rr = n - b * p.out_imgpx;
    int yo = rr / p.out_w;   int xo = rr - yo * p.out_w;
    long long pix = (long long)b * p.img_px + (long long)(yo * p.stridepix + p.y0) * p.row_px
                  + (xo * p.stridepix + p.x0);
    apixel[i] = pix * p.px_el + p.ch_off + cb;
    wsrc[i] = p.W + (long long)r * p.Cin + cb;
    lbase[i] = i * 4096 + w * 512;
  }

  f32x4 acc[8][4];
  #pragma unroll
  for (int i = 0; i < 8; ++i)
    #pragma unroll
    for (int j = 0; j < 4; ++j)
      acc[i][j] = f32x4{0.f, 0.f, 0.f, 0.f};

  const long long wstap = 256LL * p.Cin;
  const int ntap = p.k_per / p.Cin;         // 9
  const int NT = (p.Cin >> 6) * ntap;       // 72 or 81

  auto STG = [&](int buf, int i, long long aoff, long long woff){
    __builtin_amdgcn_global_load_lds(
        (AS1 void*)(p.A + apixel[i] + aoff),
        (AS3 void*)(&As[buf][lbase[i]]), 16, 0, 0);
    __builtin_amdgcn_global_load_lds(
        (AS1 void*)(wsrc[i] + woff),
        (AS3 void*)(&Bs[buf][lbase[i]]), 16, 0, 0);
  };
  auto LDA = [&](bf16x8* av, int mi0, int ks, int buf){
    #pragma unroll
    for (int m = 0; m < 4; ++m){
      int ar = wr * 128 + (mi0 + m) * 16 + c15;
      int cb = (ks * 4 + h) ^ (ar & 7);
      av[m] = *reinterpret_cast<const bf16x8*>(&As[buf][ar * 64 + cb * 8]);
    }
  };
  auto LDB = [&](bf16x8* bv, int ks, int buf){
    #pragma unroll
    for (int n = 0; n < 4; ++n){
      int br = wc * 64 + n * 16 + c15;
      int cb = (ks * 4 + h) ^ (br & 7);
      bv[n] = *reinterpret_cast<const bf16x8*>(&Bs[buf][br * 64 + cb * 8]);
    }
  };
  auto MM = [&](bf16x8* av, bf16x8* bv, int mi0){
    __builtin_amdgcn_s_setprio(1);
    #pragma unroll
    for (int m = 0; m < 4; ++m)
      #pragma unroll
      for (int n = 0; n < 4; ++n)
        acc[mi0 + m][n] = __builtin_amdgcn_mfma_f32_16x16x32_bf16(av[m], bv[n], acc[mi0 + m][n], 0, 0, 0);
    __builtin_amdgcn_s_setprio(0);
  };

  // prologue: stage kt=0 fully
  #pragma unroll
  for (int i = 0; i < 4; ++i) STG(0, i, 0, 0);

  int tap_n = 1, cib_n = 0;
  int cur = 0;

  for (int kt = 0; kt < NT; ++kt){
    const bool last = (kt == NT - 1);
    long long aoff_n = 0, woff_n = 0;
    if (!last){
      int dy = tap_n / p.tapw, dx = tap_n - dy * p.tapw;
      aoff_n = (long long)(dy * p.row_px + dx) * p.px_el + cib_n;
      woff_n = (long long)tap_n * wstap + cib_n;
    }
    bf16x8 av[4], bv[4];

    // ---- phase 0 ----
    if (!last){
      STG(cur ^ 1, 0, aoff_n, woff_n);
      asm volatile("s_waitcnt vmcnt(2)" ::: "memory");   // kt's 8 landed; kt+1 pair0 in flight
    } else {
      asm volatile("s_waitcnt vmcnt(0)" ::: "memory");
    }
    BARRIER();
    LDA(av, 0, 0, cur); LDB(bv, 0, cur);
    MM(av, bv, 0);
    BARRIER();
    // ---- phase 1 ----
    LDA(av, 4, 0, cur);
    if (!last) STG(cur ^ 1, 1, aoff_n, woff_n);
    BARRIER();
    MM(av, bv, 4);
    BARRIER();
    // ---- phase 2 ----
    LDA(av, 0, 1, cur); LDB(bv, 1, cur);
    if (!last) STG(cur ^ 1, 2, aoff_n, woff_n);
    BARRIER();
    MM(av, bv, 0);
    BARRIER();
    // ---- phase 3 ----
    LDA(av, 4, 1, cur);
    if (!last) STG(cur ^ 1, 3, aoff_n, woff_n);
    BARRIER();
    MM(av, bv, 4);
    BARRIER();

    cur ^= 1;
    if (!last){ ++tap_n; if (tap_n == ntap){ tap_n = 0; cib_n += 64; } }
  }

  // ---- epilogue ----
  const int r0 = (lane >> 4) * 4;
  #pragma unroll
  for (int mi = 0; mi < 8; ++mi){
    int nbase = mt * 256 + wr * 128 + mi * 16 + r0;
    #pragma unroll
    for (int ni = 0; ni < 4; ++ni){
      int co = wc * 64 + ni * 16 + c15;
      f32x4 a = acc[mi][ni];
      if constexpr (EPI == 0){
        float sc = p.ep_scale[co], sh = p.ep_shift[co];
        unsigned short* o = (unsigned short*)p.out;
        #pragma unroll
        for (int r = 0; r < 4; ++r){
          float v = fmaf(a[r], sc, sh); v = v > 0.f ? v : 0.f;
          o[(size_t)(nbase + r) * 256 + co] = f2bf(v);
        }
      } else {
        float sc = p.ep_scale[co], sh = p.ep_shift[co];
        float* o = (float*)p.out;
        int b = nbase / 7744; int s = nbase - b * 7744;
        float4 v;
        v.x = fmaxf(fmaf(a[0], sc, sh), 0.f);
        v.y = fmaxf(fmaf(a[1], sc, sh), 0.f);
        v.z = fmaxf(fmaf(a[2], sc, sh), 0.f);
        v.w = fmaxf(fmaf(a[3], sc, sh), 0.f);
        *reinterpret_cast<float4*>(o + ((size_t)(b * 256 + co)) * 7744 + s) = v;
      }
    }
  }
}

// ---------------------------------------------------------------- spatial mask
__global__ __launch_bounds__(256)
void mask_k(const unsigned short* __restrict__ h1, const float* __restrict__ w2,
            const float* __restrict__ b2, float* __restrict__ mask,
            unsigned short* __restrict__ FusPad)
{
  __shared__ float w[256];
  int t = threadIdx.x;
  w[t] = w2[t];
  __syncthreads();
  int n = blockIdx.x * 256 + t;
  const unsigned short* row = h1 + (size_t)n * 256;
  float s = b2[0];
  for (int c = 0; c < 256; c += 8){
    union { uint4 v; unsigned short s_[8]; } u;
    u.v = *reinterpret_cast<const uint4*>(row + c);
    #pragma unroll
    for (int j = 0; j < 8; ++j) s = fmaf(bf2f(u.s_[j]), w[c + j], s);
  }
  float m = 1.f / (1.f + __expf(-s));
  mask[n] = m;
  int b = n / 7744, sr = n - b * 7744;
  int y = sr / 88, x = sr - y * 88;
  FusPad[(((size_t)b * 90 + y + 1) * 90 + (x + 1)) * 576 + 512] = f2bf(m);
}

// ---------------------------------------------------------------- f_depth * mask -> NHWC bf16
__global__ __launch_bounds__(256)
void fdm_k(const unsigned short* __restrict__ Xpad, const float* __restrict__ mask,
           unsigned short* __restrict__ fdm)
{
  int idx = blockIdx.x * 256 + threadIdx.x;
  int n = idx >> 5, cb = idx & 31;
  int b = n / 7744, s = n - b * 7744;
  int y = s / 88, x = s - y * 88;
  size_t pix = ((size_t)(b * 90 + y + 1)) * 90 + x + 1;
  union { uint4 v; unsigned short s_[8]; } u, w;
  u.v = *reinterpret_cast<const uint4*>(Xpad + pix * 512 + 256 + cb * 8);
  float m = mask[n];
  #pragma unroll
  for (int j = 0; j < 8; ++j) w.s_[j] = f2bf(bf2f(u.s_[j]) * m);
  *reinterpret_cast<uint4*>(fdm + (size_t)n * 256 + cb * 8) = w.v;
}

// ---------------------------------------------------------------- merged split-K sum + channel LN (both sides)
__global__ __launch_bounds__(256)
void lnkvr2_k(const float* __restrict__ partA, const float* __restrict__ partB,
              const float* __restrict__ srbA, const float* __restrict__ srbB,
              const float* __restrict__ lngA, const float* __restrict__ lngB,
              const float* __restrict__ lnbA, const float* __restrict__ lnbB,
              unsigned short* __restrict__ kvrA, unsigned short* __restrict__ kvrB)
{
  int n = blockIdx.x, t = threadIdx.x;
  int side = n >= 968; n -= side * 968;
  const float* part = side ? partB : partA;
  const float* srb = side ? srbB : srbA;
  const float* lng = side ? lngB : lngA;
  const float* lnb = side ? lnbB : lnbA;
  unsigned short* kvr = side ? kvrB : kvrA;

  float v = srb[t];
  for (int s = 0; s < 8; ++s) v += part[((size_t)s * 968 + n) * 256 + t];
  float s1 = v, s2 = v * v;
  #pragma unroll
  for (int o = 1; o < 64; o <<= 1){ s1 += __shfl_xor(s1, o, 64); s2 += __shfl_xor(s2, o, 64); }
  __shared__ float a1[4], a2[4];
  if ((t & 63) == 0){ a1[t >> 6] = s1; a2[t >> 6] = s2; }
  __syncthreads();
  float t1 = a1[0] + a1[1] + a1[2] + a1[3];
  float t2 = a2[0] + a2[1] + a2[2] + a2[3];
  float mean = t1 * (1.f / 256.f);
  float var = t2 * (1.f / 256.f) - mean * mean;
  float rstd = rsqrtf(var + 1e-5f);
  kvr[(size_t)n * 256 + t] = f2bf((v - mean) * rstd * lng[t] + lnb[t]);
}

// ---------------------------------------------------------------- merged V-conv (+ K-proj) both sides
__global__ __launch_bounds__(256)
void vconv2_k(const unsigned short* __restrict__ kvrA, const unsigned short* __restrict__ kvrB,
              const unsigned short* __restrict__ vwtA, const unsigned short* __restrict__ vwtB,
              const float* __restrict__ vbA, const float* __restrict__ vbB,
              const unsigned short* __restrict__ kwtA, const unsigned short* __restrict__ kwtB,
              const float* __restrict__ kbA, const float* __restrict__ kbB,
              unsigned short* __restrict__ VBtA, unsigned short* __restrict__ VBtB,
              float* __restrict__ KBA, float* __restrict__ KBB)
{
  int n = blockIdx.x;
  int side = n >= 968; n -= side * 968;
  const unsigned short* kvr = side ? kvrB : kvrA;
  const unsigned short* vwt = side ? vwtB : vwtA;
  const float* vb = side ? vbB : vbA;
  const unsigned short* kwt = side ? kwtB : kwtA;
  const float* kbias = side ? kbB : kbA;
  unsigned short* VBt = side ? VBtB : VBtA;
  float* KB = side ? KBB : KBA;

  __shared__ float rowf[256];
  const int t = threadIdx.x;
  rowf[t] = bf2f(kvr[(size_t)n * 256 + t]);
  __syncthreads();
  float sum = vb[t];
  #pragma unroll 8
  for (int c = 0; c < 256; ++c)
    sum = fmaf(rowf[c], bf2f(vwt[(size_t)c * 256 + t]), sum);
  int b = n / 121, m = n - b * 121;
  VBt[(size_t)b * 32768 + (size_t)t * 128 + m] = f2bf(sum);

  if (t < 32){
    float ks = kbias[t];
    #pragma unroll 8
    for (int c = 0; c < 256; ++c)
      ks = fmaf(rowf[c], bf2f(kwt[c * 32 + t]), ks);
    KB[(size_t)n * 32 + t] = ks;
  }
}

// ---------------------------------------------------------------- merged MFMA attention (+fused Q-proj) + LN + residual
struct AttnS {
  const unsigned short* Qsrc;
  const unsigned short* wq;
  const float* qb;
  const float* Kbuf;
  const unsigned short* VBt;
  const float* ng;
  const float* nb;
  const float* gm;
  int qmode, resOff, outOff;
};

__global__ __launch_bounds__(512, 2)
void attn2_k(AttnS s0, AttnS s1,
             const unsigned short* __restrict__ Xpad,
             unsigned short* __restrict__ FusPad)
{
  __shared__ unsigned short Vt[2][256][64];
  __shared__ unsigned short Pl[2][128][64];
  __shared__ unsigned short Qs[128][64];
  __shared__ unsigned short Ks[128][64];
  __shared__ unsigned short Wqs[32][256];

  int bid = blockIdx.x;
  const int side = bid >= 488;
  bid -= side * 488;
  const AttnS& s = side ? s1 : s0;

  const int t = threadIdx.x;
  const int lane = t & 63;
  const int w = t >> 6;
  const int c15 = lane & 15;
  const int h = lane >> 4;

  const int b = bid / 61;
  const int rb = bid - b * 61;
  const int nb0 = rb * 128;

  const unsigned short* vsrc = s.VBt + (size_t)b * 32768;
  #pragma unroll
  for (int kt = 0; kt < 2; ++kt)
    #pragma unroll
    for (int i = 0; i < 4; ++i){
      int rowbase = i * 64 + w * 8;
      int c = rowbase + (lane >> 3);
      int mchunk = (lane & 7) ^ (c & 7);
      __builtin_amdgcn_global_load_lds(
        (AS1 void*)(vsrc + (size_t)c * 128 + kt * 64 + mchunk * 8),
        (AS3 void*)(&Vt[kt][rowbase][0]),
        16, 0, 0);
    }

  {
    uint4* d = (uint4*)&Wqs[0][0]; const uint4* sw = (const uint4*)s.wq;
    d[t] = sw[t];
    d[t + 512] = sw[t + 512];
  }
  {
    int m = t >> 2, part = t & 3;
    union { uint4 v; unsigned short s_[8]; } u;
    u.v = uint4{0, 0, 0, 0};
    if (m < 121){
      const float* kp = s.Kbuf + ((size_t)b * 121 + m) * 32 + part * 8;
      float4 a = *reinterpret_cast<const float4*>(kp);
      float4 bb = *reinterpret_cast<const float4*>(kp + 4);
      u.s_[0] = f2bf(a.x); u.s_[1] = f2bf(a.y); u.s_[2] = f2bf(a.z); u.s_[3] = f2bf(a.w);
      u.s_[4] = f2bf(bb.x); u.s_[5] = f2bf(bb.y); u.s_[6] = f2bf(bb.z); u.s_[7] = f2bf(bb.w);
    }
    *reinterpret_cast<uint4*>(&Ks[m][(part ^ (m & 7)) * 8]) = u.v;
  }
  __syncthreads();

  const int nA = w * 16 + c15;
  const float scale = 0.17677669529663687f;  // 32^-0.5

  {
    int gn = nb0 + nA; if (gn > 7743) gn = 7743;
    const unsigned short* xrow;
    if (s.qmode){
      int y = gn / 88, x = gn - y * 88;
      xrow = s.Qsrc + (((size_t)(b * 90) + y + 1) * 90 + (x + 1)) * 512;
    } else {
      xrow = s.Qsrc + ((size_t)b * 7744 + gn) * 256;
    }
    f32x4 qacc[2];
    qacc[0] = f32x4{0.f, 0.f, 0.f, 0.f};
    qacc[1] = f32x4{0.f, 0.f, 0.f, 0.f};
    #pragma unroll
    for (int kt = 0; kt < 8; ++kt){
      bf16x8 ax = *reinterpret_cast<const bf16x8*>(xrow + kt * 32 + h * 8);
      #pragma unroll
      for (int ni = 0; ni < 2; ++ni){
        int co = ni * 16 + c15;
        bf16x8 bw = *reinterpret_cast<const bf16x8*>(&Wqs[co][((kt * 4 + h) ^ (co & 7)) * 8]);
        qacc[ni] = __builtin_amdgcn_mfma_f32_16x16x32_bf16(ax, bw, qacc[ni], 0, 0, 0);
      }
    }
    #pragma unroll
    for (int ni = 0; ni < 2; ++ni){
      int co = ni * 16 + c15;
      float bq = s.qb[co];
      #pragma unroll
      for (int r = 0; r < 4; ++r){
        int n = w * 16 + 4 * h + r;
        int chunk = (co >> 3) ^ (n & 7);
        Qs[n][chunk * 8 + (co & 7)] = f2bf((qacc[ni][r] + bq) * scale);
      }
    }
  }

  bf16x8 aq = *reinterpret_cast<const bf16x8*>(&Qs[nA][(h ^ (nA & 7)) * 8]);
  f32x4 sv[8];
  #pragma unroll
  for (int ni = 0; ni < 8; ++ni){
    int mrow = ni * 16 + c15;
    bf16x8 bk = *reinterpret_cast<const bf16x8*>(&Ks[mrow][(h ^ (mrow & 7)) * 8]);
    sv[ni] = __builtin_amdgcn_mfma_f32_16x16x32_bf16(aq, bk, f32x4{0.f,0.f,0.f,0.f}, 0, 0, 0);
  }
  if (c15 >= 9) sv[7] = f32x4{-1e30f, -1e30f, -1e30f, -1e30f};

  float rden[4];
  #pragma unroll
  for (int r = 0; r < 4; ++r){
    float mx = sv[0][r];
    #pragma unroll
    for (int ni = 1; ni < 8; ++ni) mx = fmaxf(mx, sv[ni][r]);
    #pragma unroll
    for (int o = 1; o < 16; o <<= 1) mx = fmaxf(mx, __shfl_xor(mx, o, 64));
    float sm = 0.f;
    #pragma unroll
    for (int ni = 0; ni < 8; ++ni){
      float p = __expf(sv[ni][r] - mx);
      sv[ni][r] = p;
      sm += p;
    }
    #pragma unroll
    for (int o = 1; o < 16; o <<= 1) sm += __shfl_xor(sm, o, 64);
    rden[r] = 1.f / sm;
  }
  #pragma unroll
  for (int ni = 0; ni < 8; ++ni){
    int m = ni * 16 + c15;
    int kt = m >> 6;
    int mq = (m & 63) >> 3;
    #pragma unroll
    for (int r = 0; r < 4; ++r){
      int n = w * 16 + 4 * h + r;
      Pl[kt][n][(mq ^ (n & 7)) * 8 + (m & 7)] = f2bf(sv[ni][r] * rden[r]);
    }
  }

  bf16x8 pa[2][2];
  #pragma unroll
  for (int kt = 0; kt < 2; ++kt)
    #pragma unroll
    for (int ks = 0; ks < 2; ++ks)
      pa[kt][ks] = *reinterpret_cast<const bf16x8*>(&Pl[kt][nA][((ks * 4 + h) ^ (nA & 7)) * 8]);

  f32x4 acc[16];
  #pragma unroll
  for (int ni = 0; ni < 16; ++ni) acc[ni] = f32x4{0.f, 0.f, 0.f, 0.f};
  #pragma unroll
  for (int ni = 0; ni < 16; ++ni){
    int crow = ni * 16 + c15;
    #pragma unroll
    for (int kt = 0; kt < 2; ++kt)
      #pragma unroll
      for (int ks = 0; ks < 2; ++ks){
        bf16x8 bv = *reinterpret_cast<const bf16x8*>(&Vt[kt][crow][((ks * 4 + h) ^ (crow & 7)) * 8]);
        acc[ni] = __builtin_amdgcn_mfma_f32_16x16x32_bf16(pa[kt][ks], bv, acc[ni], 0, 0, 0);
      }
  }

  float ngv[16], nbb[16];
  #pragma unroll
  for (int ni = 0; ni < 16; ++ni){
    int c = ni * 16 + c15;
    ngv[ni] = s.ng[c]; nbb[ni] = s.nb[c];
  }
  float g = s.gm[0]; g = fminf(fmaxf(g, 0.f), 1.f);

  #pragma unroll
  for (int r = 0; r < 4; ++r){
    float s1 = 0.f, s2 = 0.f;
    #pragma unroll
    for (int ni = 0; ni < 16; ++ni){ float v = acc[ni][r]; s1 += v; s2 += v * v; }
    #pragma unroll
    for (int o = 1; o < 16; o <<= 1){ s1 += __shfl_xor(s1, o, 64); s2 += __shfl_xor(s2, o, 64); }
    float mean = s1 * (1.f / 256.f);
    float var = s2 * (1.f / 256.f) - mean * mean;
    float rstd = rsqrtf(var + 1e-5f);

    int nloc = w * 16 + 4 * h + r;
    int rix = nb0 + nloc;
    if (rix < 7744){
      int y = rix / 88, x = rix - y * 88;
      size_t pix = ((size_t)(b * 90) + y + 1) * 90 + (x + 1);
      const unsigned short* res = Xpad + pix * 512 + s.resOff;
      unsigned short* outp = FusPad + pix * 576 + s.outOff;
      #pragma unroll
      for (int ni = 0; ni < 16; ++ni){
        int c = ni * 16 + c15;
        float yv = (acc[ni][r] - mean) * rstd * ngv[ni] + nbb[ni];
        outp[c] = f2bf(bf2f(res[c]) + g * yv);
      }
    }
  }
}

// ================================================================ host
extern "C" void kernel_launch(void* const* d_in, const int* in_sizes, int n_in,
                              void* d_out, int out_size, void* d_ws, size_t ws_size,
                              hipStream_t stream)
{
  const float* P[42];
  for (int i = 0; i < 42; ++i) P[i] = (const float*)d_in[i];

  char* ws = (char*)d_ws;
  size_t off = 0;
  auto take = [&](size_t bytes) -> char* {
    char* p = ws + off; off += (bytes + 255) & ~(size_t)255; return p;
  };
  unsigned short* XPAD = (unsigned short*)take(8ull * 8100 * 512 * 2);   // 66.4 MB
  unsigned short* FUSP = (unsigned short*)take(8ull * 8100 * 576 * 2);   // 74.6 MB
  unsigned short* H1   = (unsigned short*)take(61952ull * 256 * 2);      // 31.7 MB
  unsigned short* FDM  = H1;  // alias: h1 dead after mask_k
  unsigned short* W1T  = (unsigned short*)take(9ull * 256 * 512 * 2);
  unsigned short* WFT  = (unsigned short*)take(9ull * 256 * 576 * 2);
  unsigned short* WSRA = (unsigned short*)take(64ull * 256 * 256 * 2);
  unsigned short* WSRB = (unsigned short*)take(64ull * 256 * 256 * 2);
  float* PARTA = (float*)take(8ull * 968 * 256 * 4);
  float* PARTB = (float*)take(8ull * 968 * 256 * 4);
  unsigned short* KVRA = (unsigned short*)take(968ull * 256 * 2);
  unsigned short* KVRB = (unsigned short*)take(968ull * 256 * 2);
  float* KBA  = (float*)take(968ull * 32 * 4);
  float* KBB  = (float*)take(968ull * 32 * 4);
  unsigned short* VBTA = (unsigned short*)take(2ull * 8 * 256 * 128 * 2);
  unsigned short* VBTB = VBTA + 8ull * 256 * 128;
  float* MASK = (float*)take(61952ull * 4);
  float* SC1 = (float*)take(256 * 4);
  float* SH1 = (float*)take(256 * 4);
  float* SCF = (float*)take(256 * 4);
  float* SHF = (float*)take(256 * 4);
  unsigned short* WQSA = (unsigned short*)take(32ull * 256 * 2);
  unsigned short* WQSB = (unsigned short*)take(32ull * 256 * 2);
  unsigned short* KWTA = (unsigned short*)take(256ull * 32 * 2);
  unsigned short* VWTA = (unsigned short*)take(256ull * 256 * 2);
  unsigned short* KWTB = (unsigned short*)take(256ull * 32 * 2);
  unsigned short* VWTB = (unsigned short*)take(256ull * 256 * 2);
  (void)ws_size; (void)in_sizes; (void)n_in; (void)out_size;

  zero_border_k<<<8 * 356, 128, 0, stream>>>(XPAD, 512);
  zero_border_k<<<8 * 356, 128, 0, stream>>>(FUSP, 576);
  zero_fustail_k<<<1936, 256, 0, stream>>>(FUSP);
  hipMemsetAsync(VBTA, 0, 2ull * 8 * 256 * 128 * 2, stream);

  bnprep_k<<<1, 256, 0, stream>>>(P[4], P[5], P[6], P[7], P[3],
                                  P[38], P[39], P[40], P[41], P[37],
                                  SC1, SH1, SCF, SHF);
  prep_xpad_k<<<7744, 256, 0, stream>>>(P[0], P[1], XPAD);
  prep_w1t_k<<<256, 256, 0, stream>>>(P[2], W1T);
  prep_wfus_k<<<256, 256, 0, stream>>>(P[36], WFT);
  prep_wsr_k<<<256, 256, 0, stream>>>(P[16], WSRA);
  prep_wsr_k<<<256, 256, 0, stream>>>(P[28], WSRB);
  wqprep_k<<<32, 256, 0, stream>>>(P[10], WQSA);
  wqprep_k<<<32, 256, 0, stream>>>(P[22], WQSB);
  tranw_k<<<8, 256, 0, stream>>>(P[12], KWTA, 32, 256);
  tranw_k<<<64, 256, 0, stream>>>(P[14], VWTA, 256, 256);
  tranw_k<<<8, 256, 0, stream>>>(P[24], KWTB, 32, 256);
  tranw_k<<<64, 256, 0, stream>>>(P[26], VWTB, 256, 256);

  // conv1 3x3 (512->256) + BN + ReLU -> h1 NHWC bf16   [256^2 8-phase]
  GemmP g1{};
  g1.A = XPAD; g1.W = W1T; g1.ep_scale = SC1; g1.ep_shift = SH1; g1.out = H1;
  g1.img_px = 8100; g1.row_px = 90; g1.px_el = 512; g1.ch_off = 0; g1.y0 = 0; g1.x0 = 0;
  g1.tapw = 3; g1.stridepix = 1; g1.out_w = 88; g1.out_imgpx = 7744;
  g1.Cin = 512; g1.Mtot = 61952; g1.Mtiles = 242; g1.Ntiles = 1; g1.k_per = 4608;
  gemm256_k<0><<<242, 512, 0, stream>>>(g1);

  mask_k<<<242, 256, 0, stream>>>(H1, P[8], P[9], MASK, FUSP);
  fdm_k<<<7744, 256, 0, stream>>>(XPAD, MASK, FDM);

  // ---------------- merged SRA pipelines ----------------
  GemmP ga{};
  ga.A = FDM; ga.W = WSRA; ga.out = nullptr;
  ga.img_px = 7744; ga.row_px = 88; ga.px_el = 256; ga.ch_off = 0; ga.y0 = 0; ga.x0 = 0;
  ga.tapw = 8; ga.stridepix = 8; ga.out_w = 11; ga.out_imgpx = 121;
  ga.Cin = 256; ga.Mtot = 968; ga.Mtiles = 8; ga.Ntiles = 2; ga.k_per = 2048;
  GemmP gb = ga;
  gb.A = XPAD; gb.W = WSRB;
  gb.img_px = 8100; gb.row_px = 90; gb.px_el = 512; gb.y0 = 1; gb.x0 = 1;
  gemm_sr_k<<<256, 256, 0, stream>>>(ga, gb, PARTA, PARTB);

  lnkvr2_k<<<1936, 256, 0, stream>>>(PARTA, PARTB, P[17], P[29], P[18], P[30],
                                     P[19], P[31], KVRA, KVRB);
  vconv2_k<<<1936, 256, 0, stream>>>(KVRA, KVRB, VWTA, VWTB, P[15], P[27],
                                     KWTA, KWTB, P[13], P[25],
                                     VBTA, VBTB, KBA, KBB);

  AttnS s0{XPAD, WQSA, P[11], KBA, VBTA, P[20], P[21], P[34], 1, 0, 0};
  AttnS s1{FDM,  WQSB, P[23], KBB, VBTB, P[32], P[33], P[35], 0, 256, 256};
  attn2_k<<<976, 512, 0, stream>>>(s0, s1, XPAD, FUSP);

  // final fused conv 3x3 (576->256) + BN + ReLU -> d_out f32 NCHW   [256^2 8-phase]
  GemmP gf{};
  gf.A = FUSP; gf.W = WFT; gf.ep_scale = SCF; gf.ep_shift = SHF; gf.out = d_out;
  gf.img_px = 8100; gf.row_px = 90; gf.px_el = 576; gf.ch_off = 0; gf.y0 = 0; gf.x0 = 0;
  gf.tapw = 3; gf.stridepix = 1; gf.out_w = 88; gf.out_imgpx = 7744;
  gf.Cin = 576; gf.Mtot = 61952; gf.Mtiles = 242; gf.Ntiles = 1; gf.k_per = 5184;
  gemm256_k<1><<<242, 512, 0, stream>>>(gf);
}